// Round 7
// baseline (406.310 us; speedup 1.0000x reference)
//
#include <hip/hip_runtime.h>

#define BB 4
#define NT 256
#define NZ 384
#define NX 384
#define NREC 128
#define NZX (NZ*NX)        // 147456
#define BNZX (BB*NZX)      // 589824
#define DT 0.001f
#define INV_DH2 0.01f      // 1/(10*10)

#define TR 24              // owned tile rows
#define TC 48              // owned tile cols
#define HALO 8
#define RR 40              // region rows = 8 waves x 5
#define RC 64              // region cols = 64 lanes
#define NTDR 16            // 384/24
#define NTDC 8             // 384/48
#define TPB 128            // tiles per batch
#define NTILE 512          // 4 batches x 128
#define NBLK 256           // each block: tile (tz,tx) of batch pb AND pb+2
#define NTHR 512
#define FSTRIDE 16
#define NWIN 32            // 32 windows x 8 steps

__global__ void wave_init(unsigned* flags) {
    int i = blockIdx.x * blockDim.x + threadIdx.x;
    if (i < NTILE * FSTRIDE) flags[i] = 0u;
}

__device__ inline float dpp_shl1(float v) {
    return __int_as_float(__builtin_amdgcn_update_dpp(
        0, __float_as_int(v), 0x130 /*WAVE_SHL1*/, 0xf, 0xf, true));
}
__device__ inline float dpp_shr1(float v) {
    return __int_as_float(__builtin_amdgcn_update_dpp(
        0, __float_as_int(v), 0x138 /*WAVE_SHR1*/, 0xf, 0xf, true));
}

// Light barrier: LDS visibility only (lgkmcnt), does NOT drain vmcnt ->
// sc1 halo prefetch loads / ring stores stay in flight across compute.
__device__ inline void bar_lds() {
    asm volatile("s_waitcnt lgkmcnt(0)" ::: "memory");
    __builtin_amdgcn_s_barrier();
}

__global__ __launch_bounds__(NTHR)
void wave_tiled(float* __restrict__ ws, const float* __restrict__ vp,
                const float* __restrict__ x,
                const int* __restrict__ src_y, const int* __restrict__ src_x,
                const int* __restrict__ rec_y, const int* __restrict__ rec_x,
                float* __restrict__ y) {
    __shared__ float bnd[2][2][16][RC];   // [tile][parity][2w+{top,bot}][col]
    __shared__ float recBuf[2*NREC][8];
    __shared__ float xs[2][NT];
    __shared__ int recLoc[2*NREC], recOut[2*NREC];
    __shared__ int recCnt;

    unsigned* flags = (unsigned*)(ws + 4*BNZX);

    const int tid = threadIdx.x;
    const int col = tid & 63;
    const int w   = tid >> 6;
    const int r0w = w * 5;
    const int blk = blockIdx.x;
    const int pb  = blk >> 7;           // 0/1
    const int rem = blk & 127;
    const int tz  = rem >> 3;           // 0..15
    const int tx  = rem & 7;            // 0..7
    const int bA = pb, bB = pb + 2;
    const int oz = tz*TR - HALO, ox = tx*TC - HALO;
    const int gx = ox + col;

    if (tid == 0) recCnt = 0;
    for (int k = tid; k < 2*2*16*RC; k += NTHR) ((float*)bnd)[k] = 0.f;
    for (int k = tid; k < NT; k += NTHR) { xs[0][k] = x[bA*NT+k]; xs[1][k] = x[bB*NT+k]; }
    __syncthreads();
    for (int r = tid; r < NREC; r += NTHR) {
        int ry = rec_y[r], rx = rec_x[r];
        if (ry/TR == tz && rx/TC == tx) {       // same positions for all batches
            int i = ry - oz, c = rx - ox;
            int p = atomicAdd(&recCnt, 2);
            recLoc[p]   = (0<<12) | (i<<6) | c;  recOut[p]   = bA*NREC + r;
            recLoc[p+1] = (1<<12) | (i<<6) | c;  recOut[p+1] = bB*NREC + r;
        }
    }
    __syncthreads();

    // per-thread receiver cache (cap 4, LDS-loop fallback); myM = m | tile<<3
    int myN = 0, myM[4], myP[4];
    bool ovf = false;
    for (int p = 0; p < recCnt; ++p) {
        int rl = recLoc[p];
        if ((rl & 63) == col) {
            int rm = ((rl >> 6) & 63) - r0w;
            if ((unsigned)rm < 5u) {
                if (myN < 4) { myM[myN] = rm | ((rl>>12)<<3); myP[myN] = p; ++myN; }
                else ovf = true;
            }
        }
    }

    // neighbor flag ids (lanes 0..7 of wave 0; others poll own flag = posted)
    const int tIdx0 = (bA<<7) | rem;
    int nb0 = tIdx0;
    if (tid < 8) {
        int d = tid + (tid >= 4);               // 0..8 skipping center
        int nz2 = tz + d/3 - 1, nx2 = tx + d%3 - 1;
        if ((unsigned)nz2 < (unsigned)NTDR && (unsigned)nx2 < (unsigned)NTDC)
            nb0 = (bA<<7) | (nz2<<3) | nx2;
    }
    const int nb1 = nb0 + 2*TPB;                // same (tz,tx) plane, batch +2

    float cur0[5], prv0[5], cur1[5], prv1[5], c2i[5];
    #pragma unroll
    for (int m = 0; m < 5; ++m) {
        cur0[m]=prv0[m]=cur1[m]=prv1[m]=0.f;
        const int gz = oz + r0w + m;
        const bool inner = (gz>0 && gz<NZ-1 && gx>0 && gx<NX-1);
        const float v = inner ? vp[gz*NX+gx]*DT : 0.f;   // vp shared by batches
        c2i[m] = v*v*INV_DH2;                   // 0 at edges -> lap auto-masked
    }
    const int sy0=src_y[bA], sx0=src_x[bA], sy1=src_y[bB], sx1=src_x[bB];
    const bool srcC0 = (gx==sx0), srcC1 = (gx==sx1);
    const int  sm0 = sy0-oz-r0w, sm1 = sy1-oz-r0w;
    const int  iuUp = (2*w-1<0)?0:2*w-1, iuDn = (2*w+2>15)?15:2*w+2;
    __syncthreads();

    auto win4 = [&](float (&cur)[5], float (&prv)[5],
                    float (&bt)[2][16][RC], const float* xsT,
                    bool srcC, int srcM, int tb, int o, int s0) {
        #pragma unroll 1
        for (int s = s0; s < s0+4; ++s) {
            const int pr = s & 1, pw = pr ^ 1;
            const float upB = bt[pr][iuUp][col];
            const float dnB = bt[pr][iuDn][col];
            float hn[5];
            #pragma unroll
            for (int m = 0; m < 5; ++m) {
                const float ce = cur[m];
                const float up = (m==0)? upB : cur[m-1];
                const float dn = (m==4)? dnB : cur[m+1];
                const float lf = dpp_shl1(ce);
                const float rt = dpp_shr1(ce);
                const float su = (up+dn)+(lf+rt);
                hn[m] = fmaf(2.f, ce, -prv[m]) + c2i[m]*fmaf(-4.f, ce, su);
            }
            #pragma unroll
            for (int m = 0; m < 5; ++m) { prv[m]=cur[m]; cur[m]=hn[m]; }
            if (srcC && (unsigned)srcM < 5u) {
                const float xv = xsT[8*o+s];
                #pragma unroll
                for (int m = 0; m < 5; ++m) if (m==srcM) cur[m]+=xv;
            }
            if (ovf) {
                for (int p = 0; p < recCnt; ++p) {
                    int rl = recLoc[p];
                    if ((rl>>12)==tb && (rl&63)==col) {
                        int rm = ((rl>>6)&63) - r0w;
                        if ((unsigned)rm<5u) {
                            float v = cur[0];
                            #pragma unroll
                            for (int m=1;m<5;++m) if (rm==m) v=cur[m];
                            recBuf[p][s] = v;
                        }
                    }
                }
            } else {
                #pragma unroll
                for (int k=0;k<4;++k) if (k<myN && (myM[k]>>3)==tb) {
                    int rm = myM[k]&7;
                    float v = cur[0];
                    #pragma unroll
                    for (int m=1;m<5;++m) if (rm==m) v=cur[m];
                    recBuf[myP[k]][s] = v;
                }
            }
            bt[pw][2*w  ][col] = cur[0];
            bt[pw][2*w+1][col] = cur[4];
            bar_lds();
        }
    };

    auto storeRing = [&](float (&cur)[5], float (&prv)[5], int b, int par) {
        float* Gc = ws + (size_t)par*2*BNZX;    // r0-verbatim mechanics
        float* Gp = Gc + BNZX;
        #pragma unroll
        for (int m = 0; m < 5; ++m) {
            const int i = r0w + m;
            const bool ring = (i>=HALO && i<RR-HALO && col>=HALO && col<RC-HALO)
                          && !(i>=2*HALO && i<RR-2*HALO && col>=2*HALO && col<RC-2*HALO);
            if (ring) {   // ring cells always in-domain
                const size_t g = (size_t)b*NZX + (size_t)(oz+i)*NX + gx;
                __hip_atomic_store(&Gc[g], cur[m], __ATOMIC_RELAXED, __HIP_MEMORY_SCOPE_AGENT);
                __hip_atomic_store(&Gp[g], prv[m], __ATOMIC_RELAXED, __HIP_MEMORY_SCOPE_AGENT);
            }
        }
    };

    auto loadHalo = [&](float (&cur)[5], float (&prv)[5], int b, int par) {
        const float* Gc = ws + (size_t)par*2*BNZX;
        const float* Gp = Gc + BNZX;
        const bool colH = (col < HALO || col >= RC-HALO);
        const bool gxIn = (gx >= 0 && gx < NX);
        #pragma unroll
        for (int m = 0; m < 5; ++m) {
            const int i = r0w + m;
            if (colH || i < HALO || i >= RR-HALO) {
                const int gz = oz + i;
                if (gxIn && gz >= 0 && gz < NZ) {   // BOTH bounds (r2 lesson)
                    const size_t g = (size_t)b*NZX + (size_t)gz*NX + gx;
                    cur[m] = __hip_atomic_load(&Gc[g], __ATOMIC_RELAXED, __HIP_MEMORY_SCOPE_AGENT);
                    prv[m] = __hip_atomic_load(&Gp[g], __ATOMIC_RELAXED, __HIP_MEMORY_SCOPE_AGENT);
                } else { cur[m]=0.f; prv[m]=0.f; }
            }
        }
    };

    auto waitF = [&](int nb, unsigned gen) {
        if (tid < 64) {
            for (;;) {
                unsigned f = __hip_atomic_load(&flags[nb*FSTRIDE],
                                 __ATOMIC_RELAXED, __HIP_MEMORY_SCOPE_AGENT);
                if (__all(f >= gen)) break;
                __builtin_amdgcn_s_sleep(1);
            }
        }
    };

    // Pipeline: exchange latency of each tile hides under the other's compute.
    #pragma unroll 1
    for (int o = 0; o < NWIN; ++o) {
        if (o > 0) {
            waitF(nb1, (unsigned)o);             // T1 flags posted long ago
            bar_lds();
            loadHalo(cur1, prv1, bB, (o-1)&1);   // issued; consumed after T0 win
        }
        win4(cur0, prv0, bnd[0], xs[0], srcC0, sm0, 0, o, 0);
        win4(cur0, prv0, bnd[0], xs[0], srcC0, sm0, 0, o, 4);
        if (o > 0) {                             // forces wait on T1 loads (hidden)
            bnd[1][0][2*w  ][col] = cur1[0];
            bnd[1][0][2*w+1][col] = cur1[4];
        }
        const bool ex = (o < NWIN-1);
        if (ex) storeRing(cur0, prv0, bA, o&1);  // drains during T1 compute
        bar_lds();                               // bnd1 refill visible
        win4(cur1, prv1, bnd[1], xs[1], srcC1, sm1, 1, o, 0);
        if (ex) {
            __syncthreads();                     // full drain: T0 ring at LLC
            if (tid == 0)
                __hip_atomic_store(&flags[tIdx0*FSTRIDE], (unsigned)(o+1),
                                   __ATOMIC_RELAXED, __HIP_MEMORY_SCOPE_AGENT);
            waitF(nb0, (unsigned)(o+1));         // neighbors flagged ~half-window ago
            bar_lds();
            loadHalo(cur0, prv0, bA, o&1);       // issued; consumed after next win4
        }
        win4(cur1, prv1, bnd[1], xs[1], srcC1, sm1, 1, o, 4);
        if (ex) {
            bnd[0][0][2*w  ][col] = cur0[0];     // forces wait on T0 loads (hidden)
            bnd[0][0][2*w+1][col] = cur0[4];
            storeRing(cur1, prv1, bB, o&1);
        }
        // y flush for window o (recBuf LDS-visible after win4's bar_lds)
        for (int k = tid; k < recCnt*8; k += NTHR) {
            int p = k >> 3, s2 = k & 7;
            y[(size_t)((o<<3)+s2)*(BB*NREC) + recOut[p]] = recBuf[p][s2];
        }
        if (ex) {
            __syncthreads();                     // drain T1 ring + y; bnd0 visible
            if (tid == 0)
                __hip_atomic_store(&flags[(tIdx0 + 2*TPB)*FSTRIDE], (unsigned)(o+1),
                                   __ATOMIC_RELAXED, __HIP_MEMORY_SCOPE_AGENT);
        }
    }
}

extern "C" void kernel_launch(void* const* d_in, const int* in_sizes, int n_in,
                              void* d_out, int out_size, void* d_ws, size_t ws_size,
                              hipStream_t stream) {
    const float* x     = (const float*)d_in[0];
    const float* vp    = (const float*)d_in[1];
    const int*   src_y = (const int*)d_in[2];
    const int*   src_x = (const int*)d_in[3];
    const int*   rec_y = (const int*)d_in[4];
    const int*   rec_x = (const int*)d_in[5];
    float* y  = (float*)d_out;
    float* ws = (float*)d_ws;   // 4*BNZX frame floats + 512*16 flag words

    wave_init<<<(NTILE*FSTRIDE + 255)/256, 256, 0, stream>>>((unsigned*)(ws + 4*BNZX));
    wave_tiled<<<NBLK, NTHR, 0, stream>>>(ws, vp, x, src_y, src_x, rec_y, rec_x, y);
}

// Round 8
// 249.092 us; speedup vs baseline: 1.6312x; 1.6312x over previous
//
#include <hip/hip_runtime.h>

#define BB 4
#define NT 256
#define NZ 384
#define NX 384
#define NREC 128
#define NZX (NZ*NX)        // 147456
#define BNZX (BB*NZX)      // 589824
#define DT 0.001f
#define INV_DH2 0.01f      // 1/(10*10)

#define TR 24              // owned tile rows
#define TC 48              // owned tile cols
#define HALO 8
#define RR 40              // region rows = 8 waves x 5
#define RC 64              // region cols = 64 lanes
#define NTDR 16            // 384/24
#define NTDC 8             // 384/48
#define NBLK 512           // 4 batches x 128 tiles -> exactly 2 blocks/CU
#define NTHR 512           // 8 waves: wave w owns rows 5w..5w+4, lane = col
#define FSTRIDE 16         // flag spread (64 B)
#define DYN_LDS 40960      // pad LDS to ~54.3KB: HW caps residency at 2/CU,
                           // 512 blocks / 256 CUs -> EXACTLY 2 each (pigeonhole)

__global__ void wave_init(unsigned* flags) {
    int i = blockIdx.x * blockDim.x + threadIdx.x;
    if (i < NBLK * FSTRIDE) flags[i] = 0u;
}

__device__ inline float dpp_shl1(float v) {
    return __int_as_float(__builtin_amdgcn_update_dpp(
        0, __float_as_int(v), 0x130 /*WAVE_SHL1*/, 0xf, 0xf, true));
}
__device__ inline float dpp_shr1(float v) {
    return __int_as_float(__builtin_amdgcn_update_dpp(
        0, __float_as_int(v), 0x138 /*WAVE_SHR1*/, 0xf, 0xf, true));
}

// r0-verbatim neighbor sync. While wave0 polls (s_sleep yields the SIMD) and
// waves 1-7 wait in s_barrier (no issue slots consumed), the co-resident
// block computes -> the exchange latency chain hides under real work.
__device__ inline void grid_sync(unsigned* flags, unsigned gen, int nbId) {
    __syncthreads();   // drains vmcnt(0): ring stores at LLC before flag store
    if (threadIdx.x < 64) {
        if (threadIdx.x == 0)
            __hip_atomic_store(&flags[blockIdx.x * FSTRIDE], gen,
                               __ATOMIC_RELAXED, __HIP_MEMORY_SCOPE_AGENT);
        for (;;) {
            unsigned f = __hip_atomic_load(&flags[nbId * FSTRIDE],
                             __ATOMIC_RELAXED, __HIP_MEMORY_SCOPE_AGENT);
            if (__all(f >= gen)) break;
            __builtin_amdgcn_s_sleep(1);
        }
    }
    __syncthreads();
}

__global__ __launch_bounds__(NTHR)
void wave_tiled(float* __restrict__ ws, const float* __restrict__ vp,
                const float* __restrict__ x,
                const int* __restrict__ src_y, const int* __restrict__ src_x,
                const int* __restrict__ rec_y, const int* __restrict__ rec_x,
                float* __restrict__ y) {
    __shared__ float bnd[2][16][RC];     // [parity][2*wave+{top,bot}][col]
    __shared__ float recBuf[NREC][8];    // receiver samples, flushed per window
    __shared__ float xs[NT];             // this batch's source trace
    __shared__ int recLoc[NREC], recOut[NREC];
    __shared__ int recCnt;

    unsigned* flags = (unsigned*)(ws + 4*BNZX);

    const int tid = threadIdx.x;
    const int col = tid & 63;
    const int w   = tid >> 6;
    const int r0w = w * 5;
    const int blk = blockIdx.x;
    const int b   = blk >> 7;            // 0..3
    const int rem = blk & 127;
    const int tz  = rem >> 3;            // 0..15
    const int tx  = rem & 7;             // 0..7
    const int oz  = tz*TR - HALO, ox = tx*TC - HALO;
    const int gx  = ox + col;
    const int sy = src_y[b], sx = src_x[b];

    if (tid == 0) recCnt = 0;
    for (int k = tid; k < 2*16*RC; k += NTHR) ((float*)bnd)[k] = 0.f;
    for (int k = tid; k < NT; k += NTHR) xs[k] = x[b*NT + k];
    __syncthreads();
    for (int r = tid; r < NREC; r += NTHR) {
        int ry = rec_y[r], rx = rec_x[r];
        if (ry/TR == tz && rx/TC == tx) {
            int p = atomicAdd(&recCnt, 1);
            recLoc[p] = ((ry - oz) << 6) | (rx - ox);
            recOut[p] = b*NREC + r;
        }
    }
    __syncthreads();

    // per-thread receiver ownership cache (cap 4, LDS-loop fallback)
    int myN = 0, myM[4], myP[4];
    bool ovf = false;
    for (int p = 0; p < recCnt; ++p) {
        int rl = recLoc[p];
        if ((rl & 63) == col) {
            int rm = (rl >> 6) - r0w;
            if ((unsigned)rm < 5u) {
                if (myN < 4) { myM[myN] = rm; myP[myN] = p; ++myN; }
                else ovf = true;
            }
        }
    }

    // neighbor ids for the sync (lanes 0..7 of wave 0; others self)
    int nbId = blk;
    if (tid < 8) {
        int d = tid + (tid >= 4);            // 0..8 skipping center 4
        int nz2 = tz + d/3 - 1, nx2 = tx + d%3 - 1;
        if ((unsigned)nz2 < (unsigned)NTDR && (unsigned)nx2 < (unsigned)NTDC)
            nbId = (b << 7) | (nz2 << 3) | nx2;
    }

    // per-thread column state: 5 rows in registers
    float cur[5], prv[5], c2i[5];
    #pragma unroll
    for (int m = 0; m < 5; ++m) {
        cur[m] = 0.f; prv[m] = 0.f;
        const int gz = oz + r0w + m;
        const bool inner = (gz > 0 && gz < NZ-1 && gx > 0 && gx < NX-1);
        const float v = inner ? vp[gz*NX + gx] * DT : 0.f;
        c2i[m] = v * v * INV_DH2;    // 0 at edges -> lap auto-masked
    }
    const bool srcCol = (gx == sx);
    const int  srcM   = sy - oz - r0w;
    const int  iuUp   = (2*w-1 < 0) ? 0 : 2*w-1;
    const int  iuDn   = (2*w+2 > 15) ? 15 : 2*w+2;
    __syncthreads();

    #pragma unroll 1
    for (int t = 0; t < NT; ++t) {
        const int pr = t & 1, pw = pr ^ 1;
        const float upB = bnd[pr][iuUp][col];
        const float dnB = bnd[pr][iuDn][col];

        float hn[5];
        #pragma unroll
        for (int m = 0; m < 5; ++m) {
            const float ce = cur[m];
            const float up = (m == 0) ? upB : cur[m-1];
            const float dn = (m == 4) ? dnB : cur[m+1];
            const float lf = dpp_shl1(ce);
            const float rt = dpp_shr1(ce);
            const float s  = (up + dn) + (lf + rt);
            hn[m] = fmaf(2.f, ce, -prv[m]) + c2i[m] * fmaf(-4.f, ce, s);
        }
        #pragma unroll
        for (int m = 0; m < 5; ++m) { prv[m] = cur[m]; cur[m] = hn[m]; }

        if (srcCol && (unsigned)srcM < 5u) {
            const float xv = xs[t];
            #pragma unroll
            for (int m = 0; m < 5; ++m) if (m == srcM) cur[m] += xv;
        }
        // receiver sampling -> LDS buffer (no global ops in the step loop)
        {
            const int s2 = t & 7;
            if (ovf) {
                for (int p = 0; p < recCnt; ++p) {
                    int rl = recLoc[p];
                    if ((rl & 63) == col) {
                        int rm = (rl >> 6) - r0w;
                        if ((unsigned)rm < 5u) {
                            float v = cur[0];
                            #pragma unroll
                            for (int m = 1; m < 5; ++m) if (rm == m) v = cur[m];
                            recBuf[p][s2] = v;
                        }
                    }
                }
            } else {
                #pragma unroll
                for (int k = 0; k < 4; ++k) {
                    if (k < myN) {
                        float v = cur[0];
                        #pragma unroll
                        for (int m = 1; m < 5; ++m) if (myM[k] == m) v = cur[m];
                        recBuf[myP[k]][s2] = v;
                    }
                }
            }
        }
        bnd[pw][2*w  ][col] = cur[0];
        bnd[pw][2*w+1][col] = cur[4];

        if ((t & 7) == 7) {
            const int o = t >> 3;
            __syncthreads();   // recBuf writes of this window visible
            for (int k = tid; k < recCnt*8; k += NTHR) {
                int p = k >> 3, s2 = k & 7;
                y[(size_t)((o<<3)+s2)*(BB*NREC) + recOut[p]] = recBuf[p][s2];
            }
            if (t < NT-1) {
                float* Gc = ws + (size_t)(o & 1) * 2*BNZX;   // ping-pong frames
                float* Gp = Gc + BNZX;
                // ring: depth [HALO,2*HALO) band of the owned region
                #pragma unroll
                for (int m = 0; m < 5; ++m) {
                    const int i = r0w + m;
                    const bool ring =
                        (i >= HALO && i < RR-HALO && col >= HALO && col < RC-HALO)
                     && !(i >= 2*HALO && i < RR-2*HALO &&
                          col >= 2*HALO && col < RC-2*HALO);
                    if (ring) {   // ring cells always in-domain
                        const size_t g = (size_t)b*NZX + (size_t)(oz+i)*NX + gx;
                        __hip_atomic_store(&Gc[g], cur[m],
                                           __ATOMIC_RELAXED, __HIP_MEMORY_SCOPE_AGENT);
                        __hip_atomic_store(&Gp[g], prv[m],
                                           __ATOMIC_RELAXED, __HIP_MEMORY_SCOPE_AGENT);
                    }
                }
                grid_sync(flags, (unsigned)(o + 1), nbId);
                const bool colH = (col < HALO || col >= RC-HALO);
                const bool gxIn = (gx >= 0 && gx < NX);
                #pragma unroll
                for (int m = 0; m < 5; ++m) {
                    const int i = r0w + m;
                    if (colH || i < HALO || i >= RR-HALO) {
                        const int gz = oz + i;
                        if (gxIn && gz >= 0 && gz < NZ) {   // BOTH bounds (r2 lesson)
                            const size_t g = (size_t)b*NZX + (size_t)gz*NX + gx;
                            cur[m] = __hip_atomic_load(&Gc[g],
                                         __ATOMIC_RELAXED, __HIP_MEMORY_SCOPE_AGENT);
                            prv[m] = __hip_atomic_load(&Gp[g],
                                         __ATOMIC_RELAXED, __HIP_MEMORY_SCOPE_AGENT);
                        } else { cur[m] = 0.f; prv[m] = 0.f; }
                    }
                }
                bnd[pw][2*w  ][col] = cur[0];
                bnd[pw][2*w+1][col] = cur[4];
            }
        }
        __syncthreads();
    }
}

extern "C" void kernel_launch(void* const* d_in, const int* in_sizes, int n_in,
                              void* d_out, int out_size, void* d_ws, size_t ws_size,
                              hipStream_t stream) {
    const float* x     = (const float*)d_in[0];
    const float* vp    = (const float*)d_in[1];
    const int*   src_y = (const int*)d_in[2];
    const int*   src_x = (const int*)d_in[3];
    const int*   rec_y = (const int*)d_in[4];
    const int*   rec_x = (const int*)d_in[5];
    float* y  = (float*)d_out;
    float* ws = (float*)d_ws;   // 4*BNZX frame floats + 512*16 flag words

    wave_init<<<(NBLK*FSTRIDE + 255)/256, 256, 0, stream>>>((unsigned*)(ws + 4*BNZX));
    // DYN_LDS bytes of (unused) dynamic LDS pad the group segment to ~54.3KB:
    // hardware can then host at most 2 blocks/CU -> exactly 2 everywhere.
    wave_tiled<<<NBLK, NTHR, DYN_LDS, stream>>>(ws, vp, x, src_y, src_x,
                                                rec_y, rec_x, y);
}

// Round 9
// 248.631 us; speedup vs baseline: 1.6342x; 1.0019x over previous
//
#include <hip/hip_runtime.h>

#define BB 4
#define NT 256
#define NZ 384
#define NX 384
#define NREC 128
#define NZX (NZ*NX)        // 147456
#define BNZX (BB*NZX)      // 589824
#define DT 0.001f
#define INV_DH2 0.01f      // 1/(10*10)

#define TR 24              // owned tile rows
#define TC 48              // owned tile cols
#define HALO 8
#define RR 40              // region rows = 8 waves x 5
#define RC 64              // region cols = 64 lanes
#define NTDR 16            // 384/24
#define NTDC 8             // 384/48
#define NBLK 512           // 4 batches x 128 tiles -> exactly 2 blocks/CU
#define NTHR 512           // 8 waves: wave w owns rows 5w..5w+4, lane = col
#define FSTRIDE 16         // flag spread (64 B)
#define DYN_LDS 40960      // pad LDS to ~54.3KB: HW caps residency at 2/CU,
                           // 512 blocks / 256 CUs -> EXACTLY 2 each (pigeonhole)

__global__ void wave_init(unsigned* flags) {
    int i = blockIdx.x * blockDim.x + threadIdx.x;
    if (i < NBLK * FSTRIDE) flags[i] = 0u;
}

__device__ inline float dpp_shl1(float v) {
    return __int_as_float(__builtin_amdgcn_update_dpp(
        0, __float_as_int(v), 0x130 /*WAVE_SHL1*/, 0xf, 0xf, true));
}
__device__ inline float dpp_shr1(float v) {
    return __int_as_float(__builtin_amdgcn_update_dpp(
        0, __float_as_int(v), 0x138 /*WAVE_SHR1*/, 0xf, 0xf, true));
}

__global__ __launch_bounds__(NTHR)
void wave_tiled(float* __restrict__ ws, const float* __restrict__ vp,
                const float* __restrict__ x,
                const int* __restrict__ src_y, const int* __restrict__ src_x,
                const int* __restrict__ rec_y, const int* __restrict__ rec_x,
                float* __restrict__ y) {
    __shared__ float bnd[2][16][RC];     // [parity][2*wave+{top,bot}][col]
    __shared__ float recBuf[NREC][8];    // receiver samples, flushed per window
    __shared__ float xs[NT];             // this batch's source trace
    __shared__ int recLoc[NREC], recOut[NREC];
    __shared__ int recCnt;

    unsigned* flags = (unsigned*)(ws + 4*BNZX);

    const int tid = threadIdx.x;
    const int col = tid & 63;
    const int w   = tid >> 6;
    const int r0w = w * 5;
    const int blk = blockIdx.x;
    const int b   = blk >> 7;            // 0..3
    const int rem = blk & 127;
    const int tz  = rem >> 3;            // 0..15
    const int tx  = rem & 7;             // 0..7
    const int oz  = tz*TR - HALO, ox = tx*TC - HALO;
    const int gx  = ox + col;
    const int sy = src_y[b], sx = src_x[b];

    if (tid == 0) recCnt = 0;
    for (int k = tid; k < 2*16*RC; k += NTHR) ((float*)bnd)[k] = 0.f;
    for (int k = tid; k < NT; k += NTHR) xs[k] = x[b*NT + k];
    __syncthreads();
    for (int r = tid; r < NREC; r += NTHR) {
        int ry = rec_y[r], rx = rec_x[r];
        if (ry/TR == tz && rx/TC == tx) {
            int p = atomicAdd(&recCnt, 1);
            recLoc[p] = ((ry - oz) << 6) | (rx - ox);
            recOut[p] = b*NREC + r;
        }
    }
    __syncthreads();

    // per-thread receiver ownership cache (cap 4, LDS-loop fallback)
    int myN = 0, myM[4], myP[4];
    bool ovf = false;
    for (int p = 0; p < recCnt; ++p) {
        int rl = recLoc[p];
        if ((rl & 63) == col) {
            int rm = (rl >> 6) - r0w;
            if ((unsigned)rm < 5u) {
                if (myN < 4) { myM[myN] = rm; myP[myN] = p; ++myN; }
                else ovf = true;
            }
        }
    }

    // neighbor ids for the sync (lanes 0..7 of wave 0; others self)
    int nbId = blk;
    if (tid < 8) {
        int d = tid + (tid >= 4);            // 0..8 skipping center 4
        int nz2 = tz + d/3 - 1, nx2 = tx + d%3 - 1;
        if ((unsigned)nz2 < (unsigned)NTDR && (unsigned)nx2 < (unsigned)NTDC)
            nbId = (b << 7) | (nz2 << 3) | nx2;
    }

    // per-thread column state: 5 rows in registers
    float cur[5], prv[5], c2i[5];
    #pragma unroll
    for (int m = 0; m < 5; ++m) {
        cur[m] = 0.f; prv[m] = 0.f;
        const int gz = oz + r0w + m;
        const bool inner = (gz > 0 && gz < NZ-1 && gx > 0 && gx < NX-1);
        const float v = inner ? vp[gz*NX + gx] * DT : 0.f;
        c2i[m] = v * v * INV_DH2;    // 0 at edges -> lap auto-masked
    }
    const bool srcCol = (gx == sx);
    const int  srcM   = sy - oz - r0w;
    const int  iuUp   = (2*w-1 < 0) ? 0 : 2*w-1;
    const int  iuDn   = (2*w+2 > 15) ? 15 : 2*w+2;
    __syncthreads();

    // --- anti-phase seed: delay the second-resident lattice group (batches
    // 2/3) by ~half an exchange window (~3 us). Both lattices then run at the
    // same average rate with a persistent wall-time offset: each block's
    // exchange wait lands mid-compute of its co-resident partner, so the CU
    // never idles. Uniform within each lattice -> no deadlock possible.
    if (b >= 2) {
        #pragma unroll 1
        for (int i = 0; i < 7; ++i) __builtin_amdgcn_s_sleep(16);  // ~7x1024 cy
    }

    #pragma unroll 1
    for (int t = 0; t < NT; ++t) {
        const int pr = t & 1, pw = pr ^ 1;
        const float upB = bnd[pr][iuUp][col];
        const float dnB = bnd[pr][iuDn][col];

        float hn[5];
        #pragma unroll
        for (int m = 0; m < 5; ++m) {
            const float ce = cur[m];
            const float up = (m == 0) ? upB : cur[m-1];
            const float dn = (m == 4) ? dnB : cur[m+1];
            const float lf = dpp_shl1(ce);
            const float rt = dpp_shr1(ce);
            const float s  = (up + dn) + (lf + rt);
            hn[m] = fmaf(2.f, ce, -prv[m]) + c2i[m] * fmaf(-4.f, ce, s);
        }
        #pragma unroll
        for (int m = 0; m < 5; ++m) { prv[m] = cur[m]; cur[m] = hn[m]; }

        if (srcCol && (unsigned)srcM < 5u) {
            const float xv = xs[t];
            #pragma unroll
            for (int m = 0; m < 5; ++m) if (m == srcM) cur[m] += xv;
        }
        // receiver sampling -> LDS buffer (no global ops in the step loop)
        {
            const int s2 = t & 7;
            if (ovf) {
                for (int p = 0; p < recCnt; ++p) {
                    int rl = recLoc[p];
                    if ((rl & 63) == col) {
                        int rm = (rl >> 6) - r0w;
                        if ((unsigned)rm < 5u) {
                            float v = cur[0];
                            #pragma unroll
                            for (int m = 1; m < 5; ++m) if (rm == m) v = cur[m];
                            recBuf[p][s2] = v;
                        }
                    }
                }
            } else {
                #pragma unroll
                for (int k = 0; k < 4; ++k) {
                    if (k < myN) {
                        float v = cur[0];
                        #pragma unroll
                        for (int m = 1; m < 5; ++m) if (myM[k] == m) v = cur[m];
                        recBuf[myP[k]][s2] = v;
                    }
                }
            }
        }
        bnd[pw][2*w  ][col] = cur[0];
        bnd[pw][2*w+1][col] = cur[4];

        if ((t & 7) == 7) {
            const int o = t >> 3;
            const bool exch = (t < NT-1);
            float* Gc = ws + (size_t)(o & 1) * 2*BNZX;   // ping-pong frames
            float* Gp = Gc + BNZX;
            if (exch) {
                // ring: depth [HALO,2*HALO) band of the owned region
                #pragma unroll
                for (int m = 0; m < 5; ++m) {
                    const int i = r0w + m;
                    const bool ring =
                        (i >= HALO && i < RR-HALO && col >= HALO && col < RC-HALO)
                     && !(i >= 2*HALO && i < RR-2*HALO &&
                          col >= 2*HALO && col < RC-2*HALO);
                    if (ring) {   // ring cells always in-domain
                        const size_t g = (size_t)b*NZX + (size_t)(oz+i)*NX + gx;
                        __hip_atomic_store(&Gc[g], cur[m],
                                           __ATOMIC_RELAXED, __HIP_MEMORY_SCOPE_AGENT);
                        __hip_atomic_store(&Gp[g], prv[m],
                                           __ATOMIC_RELAXED, __HIP_MEMORY_SCOPE_AGENT);
                    }
                }
            }
            __syncthreads();   // recBuf visible; ring stores drained (vmcnt0)
            if (exch && tid == 0)
                __hip_atomic_store(&flags[blk * FSTRIDE], (unsigned)(o + 1),
                                   __ATOMIC_RELAXED, __HIP_MEMORY_SCOPE_AGENT);
            // receiver flush overlaps the neighbor wait
            for (int k = tid; k < recCnt*8; k += NTHR) {
                int p = k >> 3, s2 = k & 7;
                y[(size_t)((o<<3)+s2)*(BB*NREC) + recOut[p]] = recBuf[p][s2];
            }
            if (exch) {
                const unsigned gen = (unsigned)(o + 1);
                if (tid < 64) {
                    for (;;) {
                        unsigned f = __hip_atomic_load(&flags[nbId * FSTRIDE],
                                         __ATOMIC_RELAXED, __HIP_MEMORY_SCOPE_AGENT);
                        if (__all(f >= gen)) break;
                        __builtin_amdgcn_s_sleep(1);
                    }
                }
                __syncthreads();
                const bool colH = (col < HALO || col >= RC-HALO);
                const bool gxIn = (gx >= 0 && gx < NX);
                #pragma unroll
                for (int m = 0; m < 5; ++m) {
                    const int i = r0w + m;
                    if (colH || i < HALO || i >= RR-HALO) {
                        const int gz = oz + i;
                        if (gxIn && gz >= 0 && gz < NZ) {   // BOTH bounds (r2 lesson)
                            const size_t g = (size_t)b*NZX + (size_t)gz*NX + gx;
                            cur[m] = __hip_atomic_load(&Gc[g],
                                         __ATOMIC_RELAXED, __HIP_MEMORY_SCOPE_AGENT);
                            prv[m] = __hip_atomic_load(&Gp[g],
                                         __ATOMIC_RELAXED, __HIP_MEMORY_SCOPE_AGENT);
                        } else { cur[m] = 0.f; prv[m] = 0.f; }
                    }
                }
                bnd[pw][2*w  ][col] = cur[0];
                bnd[pw][2*w+1][col] = cur[4];
            }
        }
        __syncthreads();
    }
}

extern "C" void kernel_launch(void* const* d_in, const int* in_sizes, int n_in,
                              void* d_out, int out_size, void* d_ws, size_t ws_size,
                              hipStream_t stream) {
    const float* x     = (const float*)d_in[0];
    const float* vp    = (const float*)d_in[1];
    const int*   src_y = (const int*)d_in[2];
    const int*   src_x = (const int*)d_in[3];
    const int*   rec_y = (const int*)d_in[4];
    const int*   rec_x = (const int*)d_in[5];
    float* y  = (float*)d_out;
    float* ws = (float*)d_ws;   // 4*BNZX frame floats + 512*16 flag words

    wave_init<<<(NBLK*FSTRIDE + 255)/256, 256, 0, stream>>>((unsigned*)(ws + 4*BNZX));
    // DYN_LDS bytes of (unused) dynamic LDS pad the group segment to ~54.3KB:
    // hardware can then host at most 2 blocks/CU -> exactly 2 everywhere.
    wave_tiled<<<NBLK, NTHR, DYN_LDS, stream>>>(ws, vp, x, src_y, src_x,
                                                rec_y, rec_x, y);
}